// Round 1
// baseline (433.367 us; speedup 1.0000x reference)
//
#include <hip/hip_runtime.h>
#include <math.h>

// Sparsemax along axis 0 of z = -exp(a) * x, x: (4096, 8192) f32 row-major.
// Column j = elements x[i*8192 + j], i = 0..4095. 8192 independent simplex
// projections. Michelot fixpoint: tau = (sum_S z - 1)/|S|; S = {z > tau};
// repeat until |S| fixed. Exact (same tau as sort-based reference).
//
// Mapping: 1 block (256 thr) per 4 consecutive columns. Each thread holds
// 16 rows x 4 cols = 64 f32 in VGPRs (float4 per row spans the 4 columns).
// Per-iteration block reduction of 8 floats (sum4 + count4) via shfl_xor +
// small LDS cross-wave combine.

constexpr int ROWS = 4096;
constexpr int COLS = 8192;
constexpr int TPB  = 256;          // threads per block
constexpr int CPB  = 4;            // columns per block
constexpr int RPT  = ROWS / TPB;   // 16 rows per thread
constexpr int WPB  = TPB / 64;     // 4 waves per block

__global__ __launch_bounds__(TPB)
void sparsemax_cols(const float* __restrict__ x, const float* __restrict__ a,
                    float* __restrict__ out)
{
    __shared__ float red[WPB][8];

    const int  tid  = threadIdx.x;
    const long col0 = (long)blockIdx.x * CPB;
    const float s   = -expf(a[0]);

    // ---- load z = s*x into registers (16B/lane, 32KiB lane stride) ----
    float z[RPT][4];
    #pragma unroll
    for (int r = 0; r < RPT; ++r) {
        const long row = tid + r * TPB;
        const float4 v = *reinterpret_cast<const float4*>(x + row * COLS + col0);
        z[r][0] = s * v.x; z[r][1] = s * v.y;
        z[r][2] = s * v.z; z[r][3] = s * v.w;
    }

    const int lane = tid & 63;
    const int wave = tid >> 6;

    // ---- Michelot iteration (first pass == full-support init via tau=-inf) ----
    float tau[4]   = {-1e30f, -1e30f, -1e30f, -1e30f};
    float prevc[4] = {-1.f, -1.f, -1.f, -1.f};

    for (int it = 0; it < 40; ++it) {
        float ps[4] = {0.f, 0.f, 0.f, 0.f};   // partial sum over support
        float pc[4] = {0.f, 0.f, 0.f, 0.f};   // partial count (exact in f32)
        #pragma unroll
        for (int r = 0; r < RPT; ++r) {
            #pragma unroll
            for (int c = 0; c < 4; ++c) {
                if (z[r][c] > tau[c]) { ps[c] += z[r][c]; pc[c] += 1.f; }
            }
        }
        // wave reduce: 64 lanes, 6 butterfly steps x 8 values
        #pragma unroll
        for (int m = 1; m < 64; m <<= 1) {
            #pragma unroll
            for (int c = 0; c < 4; ++c) {
                ps[c] += __shfl_xor(ps[c], m, 64);
                pc[c] += __shfl_xor(pc[c], m, 64);
            }
        }
        if (lane == 0) {
            #pragma unroll
            for (int c = 0; c < 4; ++c) {
                red[wave][c]     = ps[c];
                red[wave][4 + c] = pc[c];
            }
        }
        __syncthreads();
        float ts[4] = {0.f, 0.f, 0.f, 0.f};
        float tc[4] = {0.f, 0.f, 0.f, 0.f};
        #pragma unroll
        for (int w = 0; w < WPB; ++w) {
            #pragma unroll
            for (int c = 0; c < 4; ++c) {
                ts[c] += red[w][c];
                tc[c] += red[w][4 + c];
            }
        }
        bool done = true;
        #pragma unroll
        for (int c = 0; c < 4; ++c) {
            tau[c] = (ts[c] - 1.0f) / tc[c];   // tc >= 1 always (max stays in support)
            done = done && (tc[c] == prevc[c]);
            prevc[c] = tc[c];
        }
        __syncthreads();   // red[] reusable next iteration
        if (done) break;   // uniform across block (same LDS values everywhere)
    }

    // ---- epilogue: out = max(z - tau, 0) ----
    #pragma unroll
    for (int r = 0; r < RPT; ++r) {
        const long row = tid + r * TPB;
        float4 o;
        o.x = fmaxf(z[r][0] - tau[0], 0.f);
        o.y = fmaxf(z[r][1] - tau[1], 0.f);
        o.z = fmaxf(z[r][2] - tau[2], 0.f);
        o.w = fmaxf(z[r][3] - tau[3], 0.f);
        *reinterpret_cast<float4*>(out + row * COLS + col0) = o;
    }
}

extern "C" void kernel_launch(void* const* d_in, const int* in_sizes, int n_in,
                              void* d_out, int out_size, void* d_ws, size_t ws_size,
                              hipStream_t stream) {
    const float* x = (const float*)d_in[0];
    const float* a = (const float*)d_in[1];
    float* out = (float*)d_out;
    hipLaunchKernelGGL(sparsemax_cols, dim3(COLS / CPB), dim3(TPB), 0, stream,
                       x, a, out);
}

// Round 2
// 338.057 us; speedup vs baseline: 1.2819x; 1.2819x over previous
//
#include <hip/hip_runtime.h>
#include <math.h>

// Sparsemax along axis 0 of z = -exp(a)*x, x: (4096, 8192) f32 row-major.
// 8192 independent simplex projections over columns (stride-8192 elements).
//
// Michelot fixpoint: tau = (sum_S z - 1)/|S|; S = {z > tau}; iterate until
// |S| stable. Exact same tau as the sort-based reference.
//
// R2 mapping (fixes R1's 4x read / 2x write over-fetch):
//   1 block = 1024 threads = 16 consecutive columns.
//   cq = tid&3 (column quad: 4 f32 = 16B), rg = tid>>2 (row group 0..255).
//   Each thread: 16 rows (rg + k*256) x 4 cols (cq*4..cq*4+3) = 64 f32 in
//   VGPRs, loaded as float4. Lanes 0..3 of each 4-lane group cover one full
//   64B cache line -> 100% line utilization on both load and store.
//   __launch_bounds__(1024,4) -> VGPR cap 128, keeps z in registers.
//
// Per-iteration reduction: butterfly shfl_xor over masks {4,8,16,32}
// (cq-preserving) -> lanes 0..3 hold per-wave partials -> LDS (stride 36
// floats, 16B-aligned rows, <=2-way bank aliasing which is free) -> 32 lanes
// of wave 0 sum across the 16 waves -> 32-float final buffer -> all threads
// read their column's (sum,count) pair. Convergence: __syncthreads_and.

constexpr int ROWS = 4096;
constexpr int COLS = 8192;
constexpr int TPB  = 1024;          // threads per block (16 waves)
constexpr int CPB  = 16;            // columns per block
constexpr int RPT  = 16;            // rows per thread = 4096 / (1024/4)
constexpr int WPB  = TPB / 64;      // 16 waves
constexpr int RSTR = 36;            // LDS row stride in floats (16B-aligned, anti-conflict)

__global__ __launch_bounds__(TPB, 4)
void sparsemax_cols(const float* __restrict__ x, const float* __restrict__ a,
                    float* __restrict__ out)
{
    __shared__ float red[WPB * RSTR];   // per-wave partials: [wave][cq*8 + v]
    __shared__ float fin[32];           // block totals: [cq*8 + v]

    const int tid  = threadIdx.x;
    const int cq   = tid & 3;           // column quad 0..3
    const int rg   = tid >> 2;          // row group 0..255
    const int lane = tid & 63;
    const int wave = tid >> 6;

    const long col = (long)blockIdx.x * CPB + cq * 4;
    const float s  = -expf(a[0]);

    // ---- load z = s*x into registers: 16 rows x 4 cols per thread ----
    float z[RPT][4];
    #pragma unroll
    for (int k = 0; k < RPT; ++k) {
        const long row = rg + k * 256;
        const float4 v = *reinterpret_cast<const float4*>(x + row * COLS + col);
        z[k][0] = s * v.x; z[k][1] = s * v.y;
        z[k][2] = s * v.z; z[k][3] = s * v.w;
    }

    // ---- Michelot iteration ----
    float tau[4]   = {-1e30f, -1e30f, -1e30f, -1e30f};
    float prevc[4] = {-1.f, -1.f, -1.f, -1.f};

    for (int it = 0; it < 40; ++it) {
        float ps[4] = {0.f, 0.f, 0.f, 0.f};   // partial sums over support
        float pc[4] = {0.f, 0.f, 0.f, 0.f};   // partial counts (exact in f32)
        #pragma unroll
        for (int k = 0; k < RPT; ++k) {
            #pragma unroll
            for (int c = 0; c < 4; ++c) {
                if (z[k][c] > tau[c]) { ps[c] += z[k][c]; pc[c] += 1.f; }
            }
        }
        // butterfly over cq-preserving masks: reduces the 16 same-cq lanes
        #pragma unroll
        for (int m = 4; m < 64; m <<= 1) {
            #pragma unroll
            for (int c = 0; c < 4; ++c) {
                ps[c] += __shfl_xor(ps[c], m, 64);
                pc[c] += __shfl_xor(pc[c], m, 64);
            }
        }
        if (lane < 4) {   // lane == cq for lanes 0..3
            float* dst = red + wave * RSTR + lane * 8;
            *reinterpret_cast<float4*>(dst)     = make_float4(ps[0], ps[1], ps[2], ps[3]);
            *reinterpret_cast<float4*>(dst + 4) = make_float4(pc[0], pc[1], pc[2], pc[3]);
        }
        __syncthreads();
        if (tid < 32) {   // sum the 16 per-wave partials for value index tid
            float t = 0.f;
            #pragma unroll
            for (int w = 0; w < WPB; ++w) t += red[w * RSTR + tid];
            fin[tid] = t;
        }
        __syncthreads();
        const float4 ts = *reinterpret_cast<const float4*>(fin + cq * 8);
        const float4 tc = *reinterpret_cast<const float4*>(fin + cq * 8 + 4);
        tau[0] = (ts.x - 1.0f) / tc.x;
        tau[1] = (ts.y - 1.0f) / tc.y;
        tau[2] = (ts.z - 1.0f) / tc.z;
        tau[3] = (ts.w - 1.0f) / tc.w;
        int local_done = (tc.x == prevc[0]) & (tc.y == prevc[1]) &
                         (tc.z == prevc[2]) & (tc.w == prevc[3]);
        prevc[0] = tc.x; prevc[1] = tc.y; prevc[2] = tc.z; prevc[3] = tc.w;
        // uniform across block; also the barrier protecting red[] reuse
        if (__syncthreads_and(local_done)) break;
    }

    // ---- epilogue: out = max(z - tau, 0), full-line float4 stores ----
    #pragma unroll
    for (int k = 0; k < RPT; ++k) {
        const long row = rg + k * 256;
        float4 o;
        o.x = fmaxf(z[k][0] - tau[0], 0.f);
        o.y = fmaxf(z[k][1] - tau[1], 0.f);
        o.z = fmaxf(z[k][2] - tau[2], 0.f);
        o.w = fmaxf(z[k][3] - tau[3], 0.f);
        *reinterpret_cast<float4*>(out + row * COLS + col) = o;
    }
}

extern "C" void kernel_launch(void* const* d_in, const int* in_sizes, int n_in,
                              void* d_out, int out_size, void* d_ws, size_t ws_size,
                              hipStream_t stream) {
    const float* x = (const float*)d_in[0];
    const float* a = (const float*)d_in[1];
    float* out = (float*)d_out;
    hipLaunchKernelGGL(sparsemax_cols, dim3(COLS / CPB), dim3(TPB), 0, stream,
                       x, a, out);
}

// Round 3
// 286.646 us; speedup vs baseline: 1.5119x; 1.1794x over previous
//
#include <hip/hip_runtime.h>
#include <math.h>

// Sparsemax along axis 0 of z = -exp(a)*x, x: (4096, 8192) f32 row-major.
// 8192 independent simplex projections over columns.
//
// R3: candidate-prefilter. tau* >= colmax - 1 (since z_max - tau <= 1), so
// only z > colmax - 1 can be in support (~5 elements/column for this data).
//   1) block max-reduce per column
//   2) one filter scan appends candidates to LDS (atomicAdd)
//   3) one thread per column runs exact Michelot on its tiny candidate list
//   4) epilogue from registers
// Fallback: if any column exceeds candidate capacity, run the exact
// block-wide Michelot loop (R2 structure) — correctness never depends on the
// statistical bound.
//
// Mapping (unchanged from R2): 1 block = 1024 threads = 16 columns;
// cq = tid&3 picks a 16B column quad, rg = tid>>2 the row group; each thread
// holds 16 rows x 4 cols = 64 f32; 4 lanes cover a full 64B line.

constexpr int ROWS = 4096;
constexpr int COLS = 8192;
constexpr int TPB  = 1024;
constexpr int CPB  = 16;
constexpr int RPT  = 16;
constexpr int WPB  = TPB / 64;
constexpr int CAP  = 64;            // candidate capacity per column
constexpr int MSTR = 20;            // max-reduce LDS row stride (floats)
constexpr int FSTR = 36;            // fallback reduce LDS row stride

__global__ __launch_bounds__(TPB, 4)
void sparsemax_cols(const float* __restrict__ x, const float* __restrict__ a,
                    float* __restrict__ out)
{
    __shared__ float red[WPB * MSTR];    // per-wave column maxima [wave][cq*4+c]
    __shared__ float m_col[CPB];         // column maxima
    __shared__ float cand[CPB][CAP];     // candidate values per column
    __shared__ int   cnt[CPB];           // candidate counts
    __shared__ int   overflow;           // any column over capacity?
    __shared__ float tauLDS[CPB];        // solved tau per column
    __shared__ float fred[WPB * FSTR];   // fallback: per-wave (sum,count) partials
    __shared__ float ffin[32];           // fallback: block totals

    const int tid  = threadIdx.x;
    const int cq   = tid & 3;
    const int rg   = tid >> 2;
    const int lane = tid & 63;
    const int wave = tid >> 6;

    if (tid < CPB) cnt[tid] = 0;
    if (tid == 0)  overflow = 0;

    const long col = (long)blockIdx.x * CPB + cq * 4;
    const float s  = -expf(a[0]);

    // ---- load z = s*x: 16 rows x 4 cols per thread ----
    float z[RPT][4];
    #pragma unroll
    for (int k = 0; k < RPT; ++k) {
        const long row = rg + k * 256;
        const float4 v = *reinterpret_cast<const float4*>(x + row * COLS + col);
        z[k][0] = s * v.x; z[k][1] = s * v.y;
        z[k][2] = s * v.z; z[k][3] = s * v.w;
    }

    // ---- per-column max: thread-local -> wave butterfly -> cross-wave ----
    float pm[4] = {z[0][0], z[0][1], z[0][2], z[0][3]};
    #pragma unroll
    for (int k = 1; k < RPT; ++k) {
        #pragma unroll
        for (int c = 0; c < 4; ++c) pm[c] = fmaxf(pm[c], z[k][c]);
    }
    #pragma unroll
    for (int m = 4; m < 64; m <<= 1) {   // cq-preserving masks
        #pragma unroll
        for (int c = 0; c < 4; ++c) pm[c] = fmaxf(pm[c], __shfl_xor(pm[c], m, 64));
    }
    if (lane < 4) {                      // lane == cq
        #pragma unroll
        for (int c = 0; c < 4; ++c) red[wave * MSTR + lane * 4 + c] = pm[c];
    }
    __syncthreads();
    if (tid < CPB) {
        float m = red[tid];
        #pragma unroll
        for (int w = 1; w < WPB; ++w) m = fmaxf(m, red[w * MSTR + tid]);
        m_col[tid] = m;
    }
    __syncthreads();

    // ---- filter scan: append z > colmax - 1 to per-column LDS lists ----
    float thr[4];
    #pragma unroll
    for (int c = 0; c < 4; ++c) thr[c] = m_col[cq * 4 + c] - 1.0f;
    #pragma unroll
    for (int k = 0; k < RPT; ++k) {
        #pragma unroll
        for (int c = 0; c < 4; ++c) {
            const float v = z[k][c];
            if (v > thr[c]) {
                const int ci  = cq * 4 + c;
                const int idx = atomicAdd(&cnt[ci], 1);
                if (idx < CAP) cand[ci][idx] = v;
                else           overflow = 1;
            }
        }
    }
    __syncthreads();

    float tau[4];
    if (!overflow) {
        // ---- exact Michelot on tiny candidate list, 1 thread per column ----
        if (tid < CPB) {
            const int K = cnt[tid];
            float t = -1e30f, prev = -1.f;
            for (int it = 0; it < CAP + 1; ++it) {
                float ssum = 0.f, scnt = 0.f;
                for (int i = 0; i < K; ++i) {
                    const float v = cand[tid][i];
                    if (v > t) { ssum += v; scnt += 1.f; }
                }
                t = (ssum - 1.0f) / scnt;     // scnt >= 1 (max always in support)
                if (scnt == prev) break;
                prev = scnt;
            }
            tauLDS[tid] = t;
        }
        __syncthreads();
        #pragma unroll
        for (int c = 0; c < 4; ++c) tau[c] = tauLDS[cq * 4 + c];
    } else {
        // ---- fallback: exact block-wide Michelot over all 16 columns ----
        float t4[4]   = {-1e30f, -1e30f, -1e30f, -1e30f};
        float prevc[4] = {-1.f, -1.f, -1.f, -1.f};
        for (int it = 0; it < 80; ++it) {
            float ps[4] = {0.f, 0.f, 0.f, 0.f};
            float pc[4] = {0.f, 0.f, 0.f, 0.f};
            #pragma unroll
            for (int k = 0; k < RPT; ++k) {
                #pragma unroll
                for (int c = 0; c < 4; ++c) {
                    if (z[k][c] > t4[c]) { ps[c] += z[k][c]; pc[c] += 1.f; }
                }
            }
            #pragma unroll
            for (int m = 4; m < 64; m <<= 1) {
                #pragma unroll
                for (int c = 0; c < 4; ++c) {
                    ps[c] += __shfl_xor(ps[c], m, 64);
                    pc[c] += __shfl_xor(pc[c], m, 64);
                }
            }
            if (lane < 4) {
                float* dst = fred + wave * FSTR + lane * 8;
                *reinterpret_cast<float4*>(dst)     = make_float4(ps[0], ps[1], ps[2], ps[3]);
                *reinterpret_cast<float4*>(dst + 4) = make_float4(pc[0], pc[1], pc[2], pc[3]);
            }
            __syncthreads();
            if (tid < 32) {
                float t = 0.f;
                #pragma unroll
                for (int w = 0; w < WPB; ++w) t += fred[w * FSTR + tid];
                ffin[tid] = t;
            }
            __syncthreads();
            const float4 ts = *reinterpret_cast<const float4*>(ffin + cq * 8);
            const float4 tc = *reinterpret_cast<const float4*>(ffin + cq * 8 + 4);
            t4[0] = (ts.x - 1.0f) / tc.x;
            t4[1] = (ts.y - 1.0f) / tc.y;
            t4[2] = (ts.z - 1.0f) / tc.z;
            t4[3] = (ts.w - 1.0f) / tc.w;
            int done = (tc.x == prevc[0]) & (tc.y == prevc[1]) &
                       (tc.z == prevc[2]) & (tc.w == prevc[3]);
            prevc[0] = tc.x; prevc[1] = tc.y; prevc[2] = tc.z; prevc[3] = tc.w;
            if (__syncthreads_and(done)) break;
        }
        #pragma unroll
        for (int c = 0; c < 4; ++c) tau[c] = t4[c];
    }

    // ---- epilogue: out = max(z - tau, 0), full-line float4 stores ----
    #pragma unroll
    for (int k = 0; k < RPT; ++k) {
        const long row = rg + k * 256;
        float4 o;
        o.x = fmaxf(z[k][0] - tau[0], 0.f);
        o.y = fmaxf(z[k][1] - tau[1], 0.f);
        o.z = fmaxf(z[k][2] - tau[2], 0.f);
        o.w = fmaxf(z[k][3] - tau[3], 0.f);
        *reinterpret_cast<float4*>(out + row * COLS + col) = o;
    }
}

extern "C" void kernel_launch(void* const* d_in, const int* in_sizes, int n_in,
                              void* d_out, int out_size, void* d_ws, size_t ws_size,
                              hipStream_t stream) {
    const float* x = (const float*)d_in[0];
    const float* a = (const float*)d_in[1];
    float* out = (float*)d_out;
    hipLaunchKernelGGL(sparsemax_cols, dim3(COLS / CPB), dim3(TPB), 0, stream,
                       x, a, out);
}